// Round 5
// baseline (104.478 us; speedup 1.0000x reference)
//
#include <hip/hip_runtime.h>

#define BATCH  256
#define TLEN   8192
#define TPB    1024
#define LUTN   1024
#define VLO    -8.0f
#define H      0.015625f                // 16 / 1024
#define INVH   64.0f
#define UOFF   512.0f                   // -VLO / H
#define UMAX   1022.999f                // clamp so i+1 <= 1023
#define SQRT7  2.6457513110645906f
#define C1     2.6457513110645906e-6f   // sqrt(7) * 1e-6

// Structure (R5): NO weight staging, NO LDS p-record.
//  t0: every thread issues its own weight slice (regs) + x prefetch.
//  h1  : wave 0 only, metadata via in-wave shfl            (no barrier before)
//  h2  : 8 thr/output, shfl_xor reduce, all 1024 threads   (barrier 1 before)
//  s   : 16 thr/output, shfl_xor reduce                    (barrier 2 before)
//  LUT : per-thread, style from s[] LDS broadcast reads,
//        w1..w5 via uniform scalar loads, centering folded analytically
//        g[j] = a[j] - mean(a)                             (barrier 3 before)
//  interp/store                                            (barrier 4 before)
// Identity: sc*d/(sqrt(var/7)+1e-6) == d*rcp(sqrt(var)+sqrt7*1e-6)*(sc*sqrt7)

__device__ __forceinline__ float lrelu(float t) { return fmaxf(t, 0.01f * t); }

// One AdaIN-MLP layer: raw weights from GLOBAL (uniform -> s_load),
// style scale/bias from LDS s[] (ssl[2j]=scale, ssl[2j+1]=bias), centering
// folded analytically.
__device__ __forceinline__ void adain_layer(
    float h[8], const float* __restrict__ wl, const float* __restrict__ bl,
    const float* ssl)
{
    float a[8];
    #pragma unroll
    for (int j = 0; j < 8; ++j) a[j] = bl[j];
    #pragma unroll
    for (int k = 0; k < 8; ++k) {
        const float hk = h[k];
        #pragma unroll
        for (int j = 0; j < 8; ++j) a[j] = fmaf(hk, wl[k * 8 + j], a[j]);
    }
    const float mu = (((a[0] + a[1]) + (a[2] + a[3])) +
                      ((a[4] + a[5]) + (a[6] + a[7]))) * 0.125f;
    float g[8], var = 0.f;
    #pragma unroll
    for (int j = 0; j < 8; ++j) { g[j] = a[j] - mu; var = fmaf(g[j], g[j], var); }
    const float r = __builtin_amdgcn_rcpf(__builtin_amdgcn_sqrtf(var) + C1);
    #pragma unroll
    for (int j = 0; j < 8; ++j)
        h[j] = lrelu(fmaf(g[j] * r, ssl[2 * j] * SQRT7, ssl[2 * j + 1]));
}

__global__ __launch_bounds__(TPB, 4) void adain_lut_kernel(
    const float* __restrict__ x, const float* __restrict__ metadata,
    const float* __restrict__ mw1, const float* __restrict__ mb1,
    const float* __restrict__ mw2, const float* __restrict__ mb2,
    const float* __restrict__ mw3, const float* __restrict__ mb3,
    const float* __restrict__ w1, const float* __restrict__ b1,
    const float* __restrict__ w2, const float* __restrict__ b2,
    const float* __restrict__ w3, const float* __restrict__ b3,
    const float* __restrict__ w4, const float* __restrict__ b4,
    const float* __restrict__ w5, const float* __restrict__ b5,
    float* __restrict__ out)
{
    __shared__ float h1s[64];
    __shared__ float h2s[128];
    __shared__ float ss[64];
    __shared__ float lut[LUTN];

    const int b    = blockIdx.x;
    const int tid  = threadIdx.x;
    const int lane = tid & 63;

    // ---- t0: issue ALL global loads (no dependencies) ----
    const int base4 = b * (TLEN / 4) + tid;
    const float4 vx0 = ((const float4*)x)[base4];
    const float4 vx1 = ((const float4*)x)[base4 + TPB];

    // stage-2 slice: output j2 = tid>>3, k = kk2 + 8i
    const int j2 = tid >> 3, kk2 = tid & 7;
    float wr2[8];
    #pragma unroll
    for (int i = 0; i < 8; ++i) wr2[i] = mw2[(kk2 + 8 * i) * 128 + j2];
    const float bias2 = mb2[j2];

    // stage-3 slice: output j3 = tid>>4, k = kk3 + 16i
    const int j3 = tid >> 4, kk3 = tid & 15;
    float wr3[8];
    #pragma unroll
    for (int i = 0; i < 8; ++i) wr3[i] = mw3[(kk3 + 16 * i) * 64 + j3];
    const float bias3 = mb3[j3];

    // ---- h1: wave 0 only, metadata broadcast via shfl (no barrier needed) ----
    if (tid < 64) {
        const float mdv = (lane < 16) ? metadata[b * 16 + lane] : 0.f;
        float w1col[16];
        #pragma unroll
        for (int k = 0; k < 16; ++k) w1col[k] = mw1[k * 64 + lane];
        float a = mb1[lane];
        #pragma unroll
        for (int k = 0; k < 16; ++k) a = fmaf(__shfl(mdv, k), w1col[k], a);
        h1s[lane] = fmaxf(a, 0.f);
    }
    __syncthreads();                                        // barrier 1

    // ---- h2: 8 threads per output, butterfly reduce ----
    {
        float acc = 0.f;
        #pragma unroll
        for (int i = 0; i < 8; ++i) acc = fmaf(h1s[kk2 + 8 * i], wr2[i], acc);
        acc += __shfl_xor(acc, 1);
        acc += __shfl_xor(acc, 2);
        acc += __shfl_xor(acc, 4);
        if (kk2 == 0) h2s[j2] = fmaxf(acc + bias2, 0.f);
    }
    __syncthreads();                                        // barrier 2

    // ---- s: 16 threads per output, butterfly reduce ----
    {
        float acc = 0.f;
        #pragma unroll
        for (int i = 0; i < 8; ++i) acc = fmaf(h2s[kk3 + 16 * i], wr3[i], acc);
        acc += __shfl_xor(acc, 1);
        acc += __shfl_xor(acc, 2);
        acc += __shfl_xor(acc, 4);
        acc += __shfl_xor(acc, 8);
        if (kk3 == 0) ss[j3] = acc + bias3;
    }
    __syncthreads();                                        // barrier 3

    // ---- phase D: build LUT, one grid point per thread ----
    {
        // uniform (scalar-load) w1/b1 centering + A, 2B, C
        float w1v[8], b1v[8];
        #pragma unroll
        for (int j = 0; j < 8; ++j) { w1v[j] = w1[j]; b1v[j] = b1[j]; }
        const float mw = (((w1v[0] + w1v[1]) + (w1v[2] + w1v[3])) +
                          ((w1v[4] + w1v[5]) + (w1v[6] + w1v[7]))) * 0.125f;
        const float mb = (((b1v[0] + b1v[1]) + (b1v[2] + b1v[3])) +
                          ((b1v[4] + b1v[5]) + (b1v[6] + b1v[7]))) * 0.125f;
        float la[8], lc[8];
        float A = 0.f, Bv = 0.f, Cv = 0.f;
        #pragma unroll
        for (int j = 0; j < 8; ++j) {
            la[j] = w1v[j] - mw;
            lc[j] = b1v[j] - mb;
            A  = fmaf(la[j], la[j], A);
            Bv = fmaf(la[j], lc[j], Bv);
            Cv = fmaf(lc[j], lc[j], Cv);
        }
        const float B2  = 2.f * Bv;
        const float b5v = b5[0];

        const float vv  = VLO + (float)tid * H;
        const float var = fmaxf(fmaf(vv, fmaf(vv, A, B2), Cv), 0.f);
        const float r   = __builtin_amdgcn_rcpf(__builtin_amdgcn_sqrtf(var) + C1);

        float h[8];
        #pragma unroll
        for (int j = 0; j < 8; ++j) {
            const float sc1 = ss[2 * j] * SQRT7;            // layer-1 scale
            const float d   = fmaf(vv, la[j], lc[j]) * sc1;
            h[j] = lrelu(fmaf(d, r, ss[2 * j + 1]));
        }

        // three 8x8 layers: raw weights via uniform scalar loads
        adain_layer(h, w2, b2, ss + 16);
        adain_layer(h, w3, b3, ss + 32);
        adain_layer(h, w4, b4, ss + 48);

        float a = b5v;
        #pragma unroll
        for (int k = 0; k < 8; ++k) a = fmaf(h[k], w5[k], a);
        lut[tid] = lrelu(a);
    }
    __syncthreads();                                        // barrier 4

    // ---- phase E: interp the prefetched x, store (8 elems/thread) ----
    #pragma unroll
    for (int r = 0; r < 2; ++r) {
        const float4 v = r ? vx1 : vx0;
        const float vin[4] = {v.x, v.y, v.z, v.w};
        float vo[4];
        #pragma unroll
        for (int c = 0; c < 4; ++c) {
            float u = fmaf(vin[c], INVH, UOFF);             // (v - VLO) / H
            u = fminf(fmaxf(u, 0.0f), UMAX);
            const int   i = (int)u;
            const float f = u - (float)i;
            const float a = lut[i];
            const float d = lut[i + 1] - a;
            vo[c] = fmaf(f, d, a);
        }
        ((float4*)out)[base4 + r * TPB] = make_float4(vo[0], vo[1], vo[2], vo[3]);
    }
}

extern "C" void kernel_launch(void* const* d_in, const int* in_sizes, int n_in,
                              void* d_out, int out_size, void* d_ws, size_t ws_size,
                              hipStream_t stream)
{
    const float* x        = (const float*)d_in[0];
    const float* metadata = (const float*)d_in[1];
    const float* mw1      = (const float*)d_in[2];
    const float* mb1      = (const float*)d_in[3];
    const float* mw2      = (const float*)d_in[4];
    const float* mb2      = (const float*)d_in[5];
    const float* mw3      = (const float*)d_in[6];
    const float* mb3      = (const float*)d_in[7];
    const float* w1       = (const float*)d_in[8];
    const float* b1       = (const float*)d_in[9];
    const float* w2       = (const float*)d_in[10];
    const float* b2       = (const float*)d_in[11];
    const float* w3       = (const float*)d_in[12];
    const float* b3       = (const float*)d_in[13];
    const float* w4       = (const float*)d_in[14];
    const float* b4       = (const float*)d_in[15];
    const float* w5       = (const float*)d_in[16];
    const float* b5       = (const float*)d_in[17];

    adain_lut_kernel<<<BATCH, TPB, 0, stream>>>(
        x, metadata, mw1, mb1, mw2, mb2, mw3, mb3,
        w1, b1, w2, b2, w3, b3, w4, b4, w5, b5, (float*)d_out);
}

// Round 6
// 101.862 us; speedup vs baseline: 1.0257x; 1.0257x over previous
//
#include <hip/hip_runtime.h>

#define BATCH  256
#define TLEN   8192
#define TPB    1024
#define LUTN   1024
#define VLO    -8.0f
#define H      0.015625f                // 16 / 1024
#define INVH   64.0f
#define UOFF   512.0f                   // -VLO / H
#define UMAX   1022.999f                // clamp so i+1 <= 1023
#define SQRT7  2.6457513110645906f
#define C1     2.6457513110645906e-6f   // sqrt(7) * 1e-6

// LDS param record p[304] (proven layout):
//   0: la'  (8) = (w1-mean)*sc1*sqrt7      8: lc' (8) = (b1-mean)*sc1*sqrt7
//  16: sb1  (8)                           24: A, 2B, C, b5
//  32 + 88*l (l=0..2): wc(64 centered), cb(8), sc'(8, *sqrt7), sb(8)
// 296: w5 (8)
// Identity: sc*d/(sqrt(var/7)+1e-6) == d*rcp(sqrt(var)+sqrt7*1e-6)*(sc*sqrt7)
//
// R6 change vs R0 (the 101.3 us best): x prefetch is issued AFTER all
// global->LDS producer loads, pinned with sched_barrier(0).  vmcnt retires
// in issue order, so in R0 every staging ds_write waited for the 8.4 MB
// x HBM drain; now the drain overlaps the MLP chain.

__device__ __forceinline__ float rowmean8(const float* __restrict__ p) {
    return (((p[0] + p[1]) + (p[2] + p[3])) + ((p[4] + p[5]) + (p[6] + p[7]))) * 0.125f;
}
__device__ __forceinline__ float lrelu(float t) { return fmaxf(t, 0.01f * t); }

__global__ __launch_bounds__(TPB, 8) void adain_lut_kernel(
    const float* __restrict__ x, const float* __restrict__ metadata,
    const float* __restrict__ mw1, const float* __restrict__ mb1,
    const float* __restrict__ mw2, const float* __restrict__ mb2,
    const float* __restrict__ mw3, const float* __restrict__ mb3,
    const float* __restrict__ w1, const float* __restrict__ b1,
    const float* __restrict__ w2, const float* __restrict__ b2,
    const float* __restrict__ w3, const float* __restrict__ b3,
    const float* __restrict__ w4, const float* __restrict__ b4,
    const float* __restrict__ w5, const float* __restrict__ b5,
    float* __restrict__ out)
{
    __shared__ float smw1[1024];        // 16x64
    __shared__ float smw2[8192];        // 64x128
    __shared__ float smw3[8192];        // 128x64
    __shared__ float md[16];
    __shared__ float h1[64];
    __shared__ float h2[128];
    __shared__ float s[64];
    __shared__ float la[8], lc[8];
    __shared__ float p[304];
    __shared__ float lut[LUTN];

    const int b   = blockIdx.x;
    const int tid = threadIdx.x;

    // ---- issue weight-staging loads FIRST (oldest in vmcnt FIFO) ----
    float4 t2a = ((const float4*)mw2)[tid];
    float4 t2b = ((const float4*)mw2)[tid + TPB];
    float4 t3a = ((const float4*)mw3)[tid];
    float4 t3b = ((const float4*)mw3)[tid + TPB];
    float4 t1  = (tid < 256) ? ((const float4*)mw1)[tid] : make_float4(0.f, 0.f, 0.f, 0.f);

    ((float4*)smw2)[tid]       = t2a;
    ((float4*)smw2)[tid + TPB] = t2b;
    ((float4*)smw3)[tid]       = t3a;
    ((float4*)smw3)[tid + TPB] = t3b;
    if (tid < 256) ((float4*)smw1)[tid] = t1;

    // ---- phase A: metadata load || batch-independent weight centering ----
    // (all loads here are newer than the staging loads, older than x)
    if (tid < 16) {
        md[tid] = metadata[b * 16 + tid];
    } else if (tid >= 128 && tid < 192) {
        int i = tid - 128; p[32 + i]  = w2[i] - rowmean8(w2 + (i & 56));
    } else if (tid >= 192 && tid < 256) {
        int i = tid - 192; p[120 + i] = w3[i] - rowmean8(w3 + (i & 56));
    } else if (tid >= 256 && tid < 320) {
        int i = tid - 256; p[208 + i] = w4[i] - rowmean8(w4 + (i & 56));
    } else if (tid >= 320 && tid < 328) {
        int j = tid - 320; la[j] = w1[j] - rowmean8(w1); lc[j] = b1[j] - rowmean8(b1);
    } else if (tid >= 328 && tid < 336) {
        int j = tid - 328; p[96 + j]  = b2[j] - rowmean8(b2);
    } else if (tid >= 336 && tid < 344) {
        int j = tid - 336; p[184 + j] = b3[j] - rowmean8(b3);
    } else if (tid >= 344 && tid < 352) {
        int j = tid - 344; p[272 + j] = b4[j] - rowmean8(b4);
    } else if (tid >= 352 && tid < 360) {
        int j = tid - 352; p[296 + j] = w5[j];
    } else if (tid == 360) {
        p[27] = b5[0];
    }

    // ---- x prefetch: issued LAST (newest), drains under the MLP chain ----
    __builtin_amdgcn_sched_barrier(0);          // no hoisting above this point
    const int base4 = b * (TLEN / 4) + tid;
    float4 vx0 = ((const float4*)x)[base4];
    float4 vx1 = ((const float4*)x)[base4 + TPB];
    __builtin_amdgcn_sched_barrier(0);          // no sinking below this point

    __syncthreads();

    // ---- phase B: style MLP (16 -> 64 -> 128 -> 64), weights from LDS ----
    if (tid < 64) {
        float a = mb1[tid];
        #pragma unroll
        for (int k = 0; k < 16; ++k) a = fmaf(md[k], smw1[k * 64 + tid], a);
        h1[tid] = fmaxf(a, 0.f);
    }
    __syncthreads();
    if (tid < 128) {
        float a = mb2[tid];
        #pragma unroll 16
        for (int k = 0; k < 64; ++k) a = fmaf(h1[k], smw2[k * 128 + tid], a);
        h2[tid] = fmaxf(a, 0.f);
    }
    __syncthreads();
    if (tid < 64) {
        float a = mb3[tid];
        #pragma unroll 16
        for (int k = 0; k < 128; ++k) a = fmaf(h2[k], smw3[k * 64 + tid], a);
        s[tid] = a;                 // s[16L + 2c] = scale, s[16L + 2c + 1] = bias
    }
    __syncthreads();

    // ---- phase C: fold style into params ----
    if (tid < 8) {
        const float sc1 = s[2 * tid] * SQRT7;
        p[tid]      = la[tid] * sc1;
        p[8 + tid]  = lc[tid] * sc1;
        p[16 + tid] = s[2 * tid + 1];
        p[104 + tid] = s[16 + 2 * tid] * SQRT7;  p[112 + tid] = s[16 + 2 * tid + 1];
        p[192 + tid] = s[32 + 2 * tid] * SQRT7;  p[200 + tid] = s[32 + 2 * tid + 1];
        p[280 + tid] = s[48 + 2 * tid] * SQRT7;  p[288 + tid] = s[48 + 2 * tid + 1];
    } else if (tid == 8) {
        float A = 0.f, B = 0.f, C = 0.f;
        #pragma unroll
        for (int j = 0; j < 8; ++j) {
            A = fmaf(la[j], la[j], A);
            B = fmaf(la[j], lc[j], B);
            C = fmaf(lc[j], lc[j], C);
        }
        p[24] = A; p[25] = 2.f * B; p[26] = C;
    }
    __syncthreads();

    // ---- phase D: build LUT, ONE grid point per thread ----
    {
        const float4 q = *(const float4*)(p + 24);          // A, 2B, C, b5
        const float vv = VLO + (float)tid * H;

        float h[8];
        {
            const float4 a0 = *(const float4*)(p);
            const float4 a1 = *(const float4*)(p + 4);
            const float4 c0 = *(const float4*)(p + 8);
            const float4 c1 = *(const float4*)(p + 12);
            const float4 s0 = *(const float4*)(p + 16);
            const float4 s1 = *(const float4*)(p + 20);
            const float laa[8] = {a0.x,a0.y,a0.z,a0.w,a1.x,a1.y,a1.z,a1.w};
            const float lcc[8] = {c0.x,c0.y,c0.z,c0.w,c1.x,c1.y,c1.z,c1.w};
            const float sb1[8] = {s0.x,s0.y,s0.z,s0.w,s1.x,s1.y,s1.z,s1.w};
            const float var = fmaxf(fmaf(vv, fmaf(vv, q.x, q.y), q.z), 0.f);
            const float r   = __builtin_amdgcn_rcpf(__builtin_amdgcn_sqrtf(var) + C1);
            #pragma unroll
            for (int j = 0; j < 8; ++j) {
                const float d = fmaf(vv, laa[j], lcc[j]);
                h[j] = lrelu(fmaf(d, r, sb1[j]));
            }
        }

        #pragma unroll 1
        for (int l = 0; l < 3; ++l) {
            const float* __restrict__ w = p + 32 + l * 88;

            float g[8];
            {
                const float4 c0 = *(const float4*)(w + 64);
                const float4 c1 = *(const float4*)(w + 68);
                const float4 wa = *(const float4*)(w);
                const float4 wb = *(const float4*)(w + 4);
                const float hk = h[0];
                g[0] = fmaf(hk, wa.x, c0.x); g[1] = fmaf(hk, wa.y, c0.y);
                g[2] = fmaf(hk, wa.z, c0.z); g[3] = fmaf(hk, wa.w, c0.w);
                g[4] = fmaf(hk, wb.x, c1.x); g[5] = fmaf(hk, wb.y, c1.y);
                g[6] = fmaf(hk, wb.z, c1.z); g[7] = fmaf(hk, wb.w, c1.w);
            }
            #pragma unroll
            for (int k = 1; k < 8; ++k) {
                const float4 wa = *(const float4*)(w + k * 8);
                const float4 wb = *(const float4*)(w + k * 8 + 4);
                const float hk = h[k];
                g[0] = fmaf(hk, wa.x, g[0]); g[1] = fmaf(hk, wa.y, g[1]);
                g[2] = fmaf(hk, wa.z, g[2]); g[3] = fmaf(hk, wa.w, g[3]);
                g[4] = fmaf(hk, wb.x, g[4]); g[5] = fmaf(hk, wb.y, g[5]);
                g[6] = fmaf(hk, wb.z, g[6]); g[7] = fmaf(hk, wb.w, g[7]);
            }
            {
                const float4 s0 = *(const float4*)(w + 72);
                const float4 s1 = *(const float4*)(w + 76);
                const float4 t0 = *(const float4*)(w + 80);
                const float4 t1 = *(const float4*)(w + 84);
                const float sc[8] = {s0.x,s0.y,s0.z,s0.w,s1.x,s1.y,s1.z,s1.w};
                const float sb[8] = {t0.x,t0.y,t0.z,t0.w,t1.x,t1.y,t1.z,t1.w};
                float var = 0.f;
                #pragma unroll
                for (int j = 0; j < 8; ++j) var = fmaf(g[j], g[j], var);
                const float r = __builtin_amdgcn_rcpf(__builtin_amdgcn_sqrtf(var) + C1);
                #pragma unroll
                for (int j = 0; j < 8; ++j)
                    h[j] = lrelu(fmaf(g[j] * r, sc[j], sb[j]));
            }
        }

        {
            const float4 f0 = *(const float4*)(p + 296);
            const float4 f1 = *(const float4*)(p + 300);
            const float w5v[8] = {f0.x,f0.y,f0.z,f0.w,f1.x,f1.y,f1.z,f1.w};
            float a = q.w;
            #pragma unroll
            for (int k = 0; k < 8; ++k) a = fmaf(h[k], w5v[k], a);
            lut[tid] = lrelu(a);
        }
    }
    __syncthreads();

    // ---- phase E: interp the prefetched x, store (8 elems/thread) ----
    #pragma unroll
    for (int r = 0; r < 2; ++r) {
        const float4 v = r ? vx1 : vx0;
        const float vin[4] = {v.x, v.y, v.z, v.w};
        float vo[4];
        #pragma unroll
        for (int c = 0; c < 4; ++c) {
            float u = fmaf(vin[c], INVH, UOFF);             // (v - VLO) / H
            u = fminf(fmaxf(u, 0.0f), UMAX);
            const int   i = (int)u;
            const float f = u - (float)i;
            const float a = lut[i];
            const float d = lut[i + 1] - a;
            vo[c] = fmaf(f, d, a);
        }
        ((float4*)out)[base4 + r * TPB] = make_float4(vo[0], vo[1], vo[2], vo[3]);
    }
}

extern "C" void kernel_launch(void* const* d_in, const int* in_sizes, int n_in,
                              void* d_out, int out_size, void* d_ws, size_t ws_size,
                              hipStream_t stream)
{
    const float* x        = (const float*)d_in[0];
    const float* metadata = (const float*)d_in[1];
    const float* mw1      = (const float*)d_in[2];
    const float* mb1      = (const float*)d_in[3];
    const float* mw2      = (const float*)d_in[4];
    const float* mb2      = (const float*)d_in[5];
    const float* mw3      = (const float*)d_in[6];
    const float* mb3      = (const float*)d_in[7];
    const float* w1       = (const float*)d_in[8];
    const float* b1       = (const float*)d_in[9];
    const float* w2       = (const float*)d_in[10];
    const float* b2       = (const float*)d_in[11];
    const float* w3       = (const float*)d_in[12];
    const float* b3       = (const float*)d_in[13];
    const float* w4       = (const float*)d_in[14];
    const float* b4       = (const float*)d_in[15];
    const float* w5       = (const float*)d_in[16];
    const float* b5       = (const float*)d_in[17];

    adain_lut_kernel<<<BATCH, TPB, 0, stream>>>(
        x, metadata, mw1, mb1, mw2, mb2, mw3, mb3,
        w1, b1, w2, b2, w3, b3, w4, b4, w5, b5, (float*)d_out);
}